// Round 12
// baseline (311.996 us; speedup 1.0000x reference)
//
#include <hip/hip_runtime.h>
#include <hip/hip_bf16.h>
#include <math.h>

#define DIM 768
#define NTOK 4096   // B*N = 2*2048
#define SEQ 2048
#define HEADS 12
#define HD 64

using bf16x8 = __attribute__((ext_vector_type(8))) __bf16;
using f32x4  = __attribute__((ext_vector_type(4))) float;
typedef unsigned short u16;

__device__ inline u16 f2bf(float f) {
  union { float f; unsigned u; } v; v.f = f;
  unsigned r = v.u + 0x7fffu + ((v.u >> 16) & 1u);  // RNE
  return (u16)(r >> 16);
}

// packed f32x2 -> bf16x2 (v_cvt_pk_bf16_f32)
__device__ inline void pk2bf(float a, float b, u16* o0, u16* o1) {
  union { __hip_bfloat162 h; u16 u[2]; } cv;
  cv.h = __float22bfloat162_rn(make_float2(a, b));
  *o0 = cv.u[0];
  *o1 = cv.u[1];
}

// GELU, sigmoid form: x*sigmoid(1.5957691x + 0.0713548x^3); |err| < ~3e-3.
__device__ inline float gelu_t(float x) {
  float z = x * (1.5957691216f + 0.0713548162f * x * x);
  return x / (1.0f + __expf(-z));
}

// async global->LDS DMA, 16 B per lane; LDS dest = wave-uniform base + lane*16
__device__ inline void gl_lds16(const u16* g, u16* l) {
  __builtin_amdgcn_global_load_lds(
      (const __attribute__((address_space(1))) unsigned int*)g,
      (__attribute__((address_space(3))) unsigned int*)l, 16, 0, 0);
}

// ---------------- LayerNorm: fp32 in -> bf16 out ----------------
__global__ __launch_bounds__(256) void ln_kernel(const float* __restrict__ x,
                                                 const float* __restrict__ w,
                                                 const float* __restrict__ b,
                                                 u16* __restrict__ y) {
  int row = blockIdx.x;
  int t = threadIdx.x;
  const float* xr = x + (size_t)row * DIM;
  float v0 = xr[t], v1 = xr[t + 256], v2 = xr[t + 512];
  float s = v0 + v1 + v2;
  float q = v0 * v0 + v1 * v1 + v2 * v2;
  for (int o = 32; o > 0; o >>= 1) {
    s += __shfl_down(s, o, 64);
    q += __shfl_down(q, o, 64);
  }
  __shared__ float ws_[4], wq_[4], mb[2];
  int wid = t >> 6;
  if ((t & 63) == 0) { ws_[wid] = s; wq_[wid] = q; }
  __syncthreads();
  if (t == 0) {
    float S = ws_[0] + ws_[1] + ws_[2] + ws_[3];
    float Q = wq_[0] + wq_[1] + wq_[2] + wq_[3];
    float mean = S * (1.0f / DIM);
    float var = Q * (1.0f / DIM) - mean * mean;
    mb[0] = mean;
    mb[1] = rsqrtf(var + 1e-5f);
  }
  __syncthreads();
  float mean = mb[0], rstd = mb[1];
  u16* yr = y + (size_t)row * DIM;
  yr[t]       = f2bf((v0 - mean) * rstd * w[t]       + b[t]);
  yr[t + 256] = f2bf((v1 - mean) * rstd * w[t + 256] + b[t + 256]);
  yr[t + 512] = f2bf((v2 - mean) * rstd * w[t + 512] + b[t + 512]);
}

// -------- fused split-K reduce + residual + bias -> x2 (fp32) + LN -> h (bf16)
__global__ __launch_bounds__(256) void redln_kernel(
    const float* __restrict__ P0, const float* __restrict__ P1,
    const float* __restrict__ bias, const float* __restrict__ res,
    float* __restrict__ x2, const float* __restrict__ lnw,
    const float* __restrict__ lnb, u16* __restrict__ y) {
  int row = blockIdx.x;
  int t = threadIdx.x;
  size_t off = (size_t)row * DIM;
  float v[3];
#pragma unroll
  for (int k = 0; k < 3; ++k) {
    int c = t + k * 256;
    v[k] = P0[off + c] + P1[off + c] + bias[c] + res[off + c];
    x2[off + c] = v[k];
  }
  float s = v[0] + v[1] + v[2];
  float q = v[0] * v[0] + v[1] * v[1] + v[2] * v[2];
  for (int o = 32; o > 0; o >>= 1) {
    s += __shfl_down(s, o, 64);
    q += __shfl_down(q, o, 64);
  }
  __shared__ float ws_[4], wq_[4], mb[2];
  int wid = t >> 6;
  if ((t & 63) == 0) { ws_[wid] = s; wq_[wid] = q; }
  __syncthreads();
  if (t == 0) {
    float S = ws_[0] + ws_[1] + ws_[2] + ws_[3];
    float Q = wq_[0] + wq_[1] + wq_[2] + wq_[3];
    float mean = S * (1.0f / DIM);
    float var = Q * (1.0f / DIM) - mean * mean;
    mb[0] = mean;
    mb[1] = rsqrtf(var + 1e-5f);
  }
  __syncthreads();
  float mean = mb[0], rstd = mb[1];
#pragma unroll
  for (int k = 0; k < 3; ++k) {
    int c = t + k * 256;
    y[off + c] = f2bf((v[k] - mean) * rstd * lnw[c] + lnb[c]);
  }
}

// ---------------- all 4 weight converts in one launch (dims compile-time) ----
__global__ __launch_bounds__(256) void wcvt_all(
    const float* __restrict__ W0, const float* __restrict__ W1,
    const float* __restrict__ W2, const float* __restrict__ W3,
    u16* __restrict__ T0, u16* __restrict__ T1,
    u16* __restrict__ T2, u16* __restrict__ T3) {
  int id = blockIdx.x;
  const float* W; u16* Wt; int K, N, local;
  if (id < 1728)      { W = W0; Wt = T0; K = 768;  N = 2304; local = id; }
  else if (id < 2304) { W = W1; Wt = T1; K = 768;  N = 768;  local = id - 1728; }
  else if (id < 4608) { W = W2; Wt = T2; K = 768;  N = 3072; local = id - 2304; }
  else                { W = W3; Wt = T3; K = 3072; N = 768;  local = id - 4608; }
  int ntiles = N / 32;
  int n0 = (local % ntiles) * 32, k0 = (local / ntiles) * 32;
  __shared__ float tile[32][33];
  int tid = threadIdx.x;
  int c = tid & 31, r8 = tid >> 5;
#pragma unroll
  for (int p = 0; p < 4; ++p) {
    int k = r8 + p * 8;
    tile[k][c] = W[(size_t)(k0 + k) * N + n0 + c];
  }
  __syncthreads();
#pragma unroll
  for (int p = 0; p < 4; ++p) {
    int n = r8 + p * 8;
    Wt[(size_t)(n0 + n) * K + k0 + c] = f2bf(tile[c][n]);
  }
}

// ---------------- V transpose: qkvB V-slice -> vT[b][v][j] ----------------
__global__ __launch_bounds__(256) void vtr_kernel(const u16* __restrict__ qkvB,
                                                  u16* __restrict__ vT) {
  __shared__ u16 tile[32][33];
  int v0 = blockIdx.x * 32, j0 = blockIdx.y * 32, b = blockIdx.z;
  int tid = threadIdx.x;
  int c = tid & 31, r8 = tid >> 5;
#pragma unroll
  for (int p = 0; p < 4; ++p) {
    int r = r8 + p * 8;
    tile[r][c] = qkvB[((size_t)(b * SEQ + j0 + r)) * 2304 + 1536 + v0 + c];
  }
  __syncthreads();
#pragma unroll
  for (int p = 0; p < 4; ++p) {
    int r = r8 + p * 8;
    vT[((size_t)(b * 768 + v0 + r)) * SEQ + j0 + c] = tile[c][r];
  }
}

// ---------------- bf16 MFMA GEMM (full-K): Cb = act(A * Bt^T + bias) --------
// BK=64, DMA staging with XOR column swizzle (verified r11, bit-identical).
__global__ __launch_bounds__(256) void bgemm_kernel(
    const u16* __restrict__ A, const u16* __restrict__ Bt,
    const float* __restrict__ bias, u16* __restrict__ Cb,
    int M, int N, int K, int act) {
  __shared__ __align__(16) u16 Asl[128 * 64];
  __shared__ __align__(16) u16 Bsl[128 * 64];
  int tid = threadIdx.x;
  int lane = tid & 63, wave = tid >> 6;
  int wm = wave >> 1, wn = wave & 1;
  int bm = blockIdx.y * 128, bn = blockIdx.x * 128;
  int l15 = lane & 15, quad = lane >> 4;
  int sm8 = tid >> 3;
  int kgx = (tid & 7) ^ (sm8 & 7);

  f32x4 acc[4][4] = {};
  const u16* Ap = A + (size_t)(bm + sm8) * K + kgx * 8;
  const u16* Bp = Bt + (size_t)(bn + sm8) * K + kgx * 8;
  u16* Al = &Asl[(wave * 8) * 64];
  u16* Bl = &Bsl[(wave * 8) * 64];
  int xr = l15 & 7;

  for (int k0 = 0; k0 < K; k0 += 64) {
#pragma unroll
    for (int p = 0; p < 4; ++p)
      gl_lds16(Ap + (size_t)(p * 32) * K + k0, Al + p * 32 * 64);
#pragma unroll
    for (int p = 0; p < 4; ++p)
      gl_lds16(Bp + (size_t)(p * 32) * K + k0, Bl + p * 32 * 64);
    __syncthreads();
#pragma unroll
    for (int ks = 0; ks < 2; ++ks) {
      int pu = ((ks << 2) + quad) ^ xr;
      bf16x8 af[4], bfr[4];
#pragma unroll
      for (int i = 0; i < 4; ++i) {
        af[i]  = *(const bf16x8*)&Asl[(wm * 64 + i * 16 + l15) * 64 + pu * 8];
        bfr[i] = *(const bf16x8*)&Bsl[(wn * 64 + i * 16 + l15) * 64 + pu * 8];
      }
#pragma unroll
      for (int i = 0; i < 4; ++i)
#pragma unroll
        for (int j = 0; j < 4; ++j)
          acc[i][j] = __builtin_amdgcn_mfma_f32_16x16x32_bf16(af[i], bfr[j], acc[i][j], 0, 0, 0);
    }
    __syncthreads();
  }

#pragma unroll
  for (int i = 0; i < 4; ++i) {
#pragma unroll
    for (int j = 0; j < 4; ++j) {
      int n = bn + wn * 64 + j * 16 + l15;
      float bv = bias[n];
      float val[4];
#pragma unroll
      for (int r = 0; r < 4; ++r) {
        float v = acc[i][j][r] + bv;
        val[r] = act ? gelu_t(v) : v;
      }
      u16 c0, c1, c2, c3;
      pk2bf(val[0], val[1], &c0, &c1);
      pk2bf(val[2], val[3], &c2, &c3);
      size_t mbase = (size_t)(bm + wm * 64 + i * 16 + quad * 4) * N + n;
      Cb[mbase]         = c0;
      Cb[mbase + N]     = c1;
      Cb[mbase + 2 * N] = c2;
      Cb[mbase + 3 * N] = c3;
    }
  }
}

// ---------------- bf16 MFMA GEMM, split-K x2, 128x64 tile, BK=64 ------------
__global__ __launch_bounds__(256) void bgemm_splitk(
    const u16* __restrict__ A, const u16* __restrict__ Bt,
    float* __restrict__ P0, float* __restrict__ P1,
    int M, int N, int K) {
  __shared__ __align__(16) u16 Asl[128 * 64];
  __shared__ __align__(16) u16 Bsl[64 * 64];
  int tid = threadIdx.x;
  int lane = tid & 63, wave = tid >> 6;
  int wm = wave >> 1, wn = wave & 1;
  int bm = blockIdx.y * 128, bn = blockIdx.x * 64;
  int l15 = lane & 15, quad = lane >> 4;
  int sm8 = tid >> 3;
  int kgx = (tid & 7) ^ (sm8 & 7);
  int half = K >> 1;
  int kbeg = blockIdx.z * half;

  f32x4 acc[4][2] = {};
  const u16* Ap = A + (size_t)(bm + sm8) * K + kbeg + kgx * 8;
  const u16* Bp = Bt + (size_t)(bn + sm8) * K + kbeg + kgx * 8;
  u16* Al = &Asl[(wave * 8) * 64];
  u16* Bl = &Bsl[(wave * 8) * 64];
  int xr = l15 & 7;

  for (int k0 = 0; k0 < half; k0 += 64) {
#pragma unroll
    for (int p = 0; p < 4; ++p)
      gl_lds16(Ap + (size_t)(p * 32) * K + k0, Al + p * 32 * 64);
#pragma unroll
    for (int p = 0; p < 2; ++p)
      gl_lds16(Bp + (size_t)(p * 32) * K + k0, Bl + p * 32 * 64);
    __syncthreads();
#pragma unroll
    for (int ks = 0; ks < 2; ++ks) {
      int pu = ((ks << 2) + quad) ^ xr;
      bf16x8 af[4], bfr[2];
#pragma unroll
      for (int i = 0; i < 4; ++i)
        af[i] = *(const bf16x8*)&Asl[(wm * 64 + i * 16 + l15) * 64 + pu * 8];
#pragma unroll
      for (int j = 0; j < 2; ++j)
        bfr[j] = *(const bf16x8*)&Bsl[(wn * 32 + j * 16 + l15) * 64 + pu * 8];
#pragma unroll
      for (int i = 0; i < 4; ++i)
#pragma unroll
        for (int j = 0; j < 2; ++j)
          acc[i][j] = __builtin_amdgcn_mfma_f32_16x16x32_bf16(af[i], bfr[j], acc[i][j], 0, 0, 0);
    }
    __syncthreads();
  }

  float* P = blockIdx.z ? P1 : P0;
#pragma unroll
  for (int i = 0; i < 4; ++i) {
#pragma unroll
    for (int j = 0; j < 2; ++j) {
      int n = bn + wn * 32 + j * 16 + l15;
#pragma unroll
      for (int r = 0; r < 4; ++r) {
        int m = bm + wm * 64 + i * 16 + quad * 4 + r;
        P[(size_t)m * N + n] = acc[i][j][r];
      }
    }
  }
}

// ---------------- split-K reduce: O = P0 + P1 + bias + res ------------------
__global__ __launch_bounds__(256) void red_kernel(
    const float* P0, const float* __restrict__ P1,
    const float* __restrict__ bias, const float* __restrict__ res,
    float* O, int Ncols) {
  int i = blockIdx.x * 256 + threadIdx.x;
  float4 a = ((const float4*)P0)[i];
  float4 b = ((const float4*)P1)[i];
  float4 r = ((const float4*)res)[i];
  int col = (i * 4) % Ncols;
  float4 bi = *(const float4*)&bias[col];
  float4 o;
  o.x = a.x + b.x + r.x + bi.x;
  o.y = a.y + b.y + r.y + bi.y;
  o.z = a.z + b.z + r.z + bi.z;
  o.w = a.w + b.w + r.w + bi.w;
  ((float4*)O)[i] = o;
}

// ---------------- single-wave MFMA flash attention ----------------
// One wave (64 thr) per 64-query block: K/V/P fragments amortized over all
// four 16-row bands; double-buffered K/V staging via global_load_lds with the
// r11-verified XOR column swizzle (stride-64 rows, unit p holds global unit
// p^(row&7)); P uses the r6/r9-verified AST=72 block-of-16 jt^quad swizzle.
// __syncthreads with 1 wave = cheap vmcnt drain only; P write->read relies on
// wave-ordered DS (r3-r6 proven) + a compiler memory barrier.
#define AST 72
__global__ __launch_bounds__(64) void attn_kernel(const u16* __restrict__ qkv,
                                                  const u16* __restrict__ vT,
                                                  u16* __restrict__ out) {
  __shared__ __align__(16) u16 Qs[64 * 64];
  __shared__ __align__(16) u16 Ks[2][64 * 64];
  __shared__ __align__(16) u16 Vs[2][64 * 64];
  __shared__ u16 Ps[64 * AST];

  int tid = threadIdx.x;                 // 0..63 (one wave)
  int l15 = tid & 15, quad = tid >> 4;
  int qt = blockIdx.x * 64;
  int h = blockIdx.y, b = blockIdx.z;
  size_t base = (size_t)b * SEQ;
  int srow = tid >> 3;                   // staging row 0..7 within 8-row group
  int sux = (tid & 7) ^ (srow & 7);      // XOR-swizzled global 16B col-unit
  const u16* qbase = qkv + (base + qt) * 2304 + h * HD;
  const u16* kbase = qkv + base * 2304 + 768 + h * HD;
  const u16* vbase = vT + ((size_t)(b * HEADS + h) * HD) * SEQ;

  // stage Q (8 DMAs) + K/V tile 0 (16 DMAs)
#pragma unroll
  for (int p = 0; p < 8; ++p)
    gl_lds16(qbase + (size_t)(p * 8 + srow) * 2304 + sux * 8, Qs + p * 8 * 64);
#pragma unroll
  for (int p = 0; p < 8; ++p) {
    gl_lds16(kbase + (size_t)(p * 8 + srow) * 2304 + sux * 8, Ks[0] + p * 8 * 64);
    gl_lds16(vbase + (size_t)(p * 8 + srow) * SEQ + sux * 8, Vs[0] + p * 8 * 64);
  }
  __syncthreads();

  int xr = l15 & 7;
  // hoist Q A-frags: row = it*16+l15, unit = (ks*4+quad)^(row&7)
  bf16x8 aq[4][2];
#pragma unroll
  for (int it = 0; it < 4; ++it)
#pragma unroll
    for (int ks = 0; ks < 2; ++ks)
      aq[it][ks] = *(const bf16x8*)&Qs[(it * 16 + l15) * 64 + (((ks << 2) + quad) ^ xr) * 8];

  f32x4 o_acc[4][4] = {};
  float l_part[4][4] = {};
  int sw = l15 >> 2;

  for (int t = 0; t < 32; ++t) {
    int buf = t & 1;
    if (t + 1 < 32) {
      size_t kt1 = (size_t)(t + 1) * 64;
#pragma unroll
      for (int p = 0; p < 8; ++p) {
        gl_lds16(kbase + (kt1 + p * 8 + srow) * 2304 + sux * 8, Ks[buf ^ 1] + p * 8 * 64);
        gl_lds16(vbase + (size_t)(p * 8 + srow) * SEQ + kt1 + sux * 8, Vs[buf ^ 1] + p * 8 * 64);
      }
    }

    // K B-frags (shared across all 4 q-bands)
    bf16x8 bk[4][2];
#pragma unroll
    for (int jt = 0; jt < 4; ++jt)
#pragma unroll
      for (int ks = 0; ks < 2; ++ks)
        bk[jt][ks] = *(const bf16x8*)&Ks[buf][(jt * 16 + l15) * 64 + (((ks << 2) + quad) ^ xr) * 8];

    // per band: S = Q K^T, max-free softmax, P write (bf16, jt^quad swizzle)
#pragma unroll
    for (int it = 0; it < 4; ++it) {
      f32x4 s_acc[4] = {};
#pragma unroll
      for (int jt = 0; jt < 4; ++jt) {
        s_acc[jt] = __builtin_amdgcn_mfma_f32_16x16x32_bf16(aq[it][0], bk[jt][0], s_acc[jt], 0, 0, 0);
        s_acc[jt] = __builtin_amdgcn_mfma_f32_16x16x32_bf16(aq[it][1], bk[jt][1], s_acc[jt], 0, 0, 0);
      }
#pragma unroll
      for (int r = 0; r < 4; ++r) {
        float p0 = __expf(s_acc[0][r] * 0.125f);
        float p1 = __expf(s_acc[1][r] * 0.125f);
        float p2 = __expf(s_acc[2][r] * 0.125f);
        float p3 = __expf(s_acc[3][r] * 0.125f);
        l_part[it][r] += p0 + p1 + p2 + p3;
        u16 b0, b1, b2, b3;
        pk2bf(p0, p1, &b0, &b1);
        pk2bf(p2, p3, &b2, &b3);
        int prow = (it * 16 + quad * 4 + r) * AST;
        Ps[prow + ((0 ^ quad) * 16) + l15] = b0;
        Ps[prow + ((1 ^ quad) * 16) + l15] = b1;
        Ps[prow + ((2 ^ quad) * 16) + l15] = b2;
        Ps[prow + ((3 ^ quad) * 16) + l15] = b3;
      }
    }
    __asm__ volatile("" ::: "memory");  // order P stores before P loads (wave-ordered DS in HW)

    // O += P V  (V B-frags shared across bands)
#pragma unroll
    for (int ks = 0; ks < 2; ++ks) {
      int blk = ks * 2 + (quad >> 1);
      bf16x8 bv[4];
#pragma unroll
      for (int dt = 0; dt < 4; ++dt)
        bv[dt] = *(const bf16x8*)&Vs[buf][(dt * 16 + l15) * 64 + (((ks << 2) + quad) ^ xr) * 8];
#pragma unroll
      for (int it = 0; it < 4; ++it) {
        bf16x8 ap = *(const bf16x8*)&Ps[(it * 16 + l15) * AST + ((blk ^ sw) * 16) + (quad & 1) * 8];
#pragma unroll
        for (int dt = 0; dt < 4; ++dt)
          o_acc[it][dt] = __builtin_amdgcn_mfma_f32_16x16x32_bf16(ap, bv[dt], o_acc[it][dt], 0, 0, 0);
      }
    }
    __syncthreads();  // 1-wave: cheap drain of prefetch DMAs (vmcnt) + LDS order
  }

  // epilogue: l reduction (butterfly over the 16 l15 lanes) + bf16 output
#pragma unroll
  for (int it = 0; it < 4; ++it) {
#pragma unroll
    for (int r = 0; r < 4; ++r) {
      float l = l_part[it][r];
      for (int msk = 1; msk < 16; msk <<= 1) l += __shfl_xor(l, msk, 64);
      float inv = 1.0f / l;
      size_t trow = (base + qt + it * 16 + quad * 4 + r) * DIM + h * HD;
      u16 c0, c1, c2, c3;
      pk2bf(o_acc[it][0][r] * inv, o_acc[it][1][r] * inv, &c0, &c1);
      pk2bf(o_acc[it][2][r] * inv, o_acc[it][3][r] * inv, &c2, &c3);
      out[trow + 0 * 16 + l15] = c0;
      out[trow + 1 * 16 + l15] = c1;
      out[trow + 2 * 16 + l15] = c2;
      out[trow + 3 * 16 + l15] = c3;
    }
  }
}

extern "C" void kernel_launch(void* const* d_in, const int* in_sizes, int n_in,
                              void* d_out, int out_size, void* d_ws, size_t ws_size,
                              hipStream_t stream) {
  const float* x     = (const float*)d_in[0];
  const float* ln1w  = (const float*)d_in[1];
  const float* ln1b  = (const float*)d_in[2];
  const float* qkvw  = (const float*)d_in[3];
  const float* qkvbi = (const float*)d_in[4];
  const float* projw = (const float*)d_in[5];
  const float* projb = (const float*)d_in[6];
  const float* ln2w  = (const float*)d_in[7];
  const float* ln2b  = (const float*)d_in[8];
  const float* l1w   = (const float*)d_in[9];
  const float* l1b   = (const float*)d_in[10];
  const float* l2w   = (const float*)d_in[11];
  const float* l2b   = (const float*)d_in[12];
  float* out = (float*)d_out;

  char* w = (char*)d_ws;
  u16*   h     = (u16*)w;   w += (size_t)NTOK * DIM * 2;          // 6.3 MB
  u16*   qkvB  = (u16*)w;                                         // 18.9 MB (union)
  u16*   mid   = (u16*)w;   w += (size_t)NTOK * 3072 * 2;         // 25.2 MB union
  u16*   attnb = (u16*)w;   w += (size_t)NTOK * DIM * 2;          // 6.3 MB
  float* x2    = (float*)w; w += (size_t)NTOK * DIM * 4;          // 12.6 MB
  u16*   vTb   = (u16*)w;   w += (size_t)NTOK * DIM * 2;          // 6.3 MB
  u16*   qkvwt = (u16*)w;   w += (size_t)DIM * 2304 * 2;
  u16*   projwt= (u16*)w;   w += (size_t)DIM * DIM * 2;
  u16*   l1wt  = (u16*)w;   w += (size_t)DIM * 3072 * 2;
  u16*   l2wt  = (u16*)w;   w += (size_t)3072 * DIM * 2;
  float* Pbuf  = (float*)w; w += (size_t)NTOK * DIM * 4;          // 12.6 MB (split-K P1)

  wcvt_all<<<6912, 256, 0, stream>>>(qkvw, projw, l1w, l2w,
                                     qkvwt, projwt, l1wt, l2wt);

  ln_kernel<<<NTOK, 256, 0, stream>>>(x, ln1w, ln1b, h);
  bgemm_kernel<<<dim3(2304 / 128, NTOK / 128), 256, 0, stream>>>(
      h, qkvwt, qkvbi, qkvB, NTOK, 2304, DIM, 0);
  vtr_kernel<<<dim3(768 / 32, SEQ / 32, 2), 256, 0, stream>>>(qkvB, vTb);
  attn_kernel<<<dim3(SEQ / 64, HEADS, 2), 64, 0, stream>>>(qkvB, vTb, attnb);

  // proj: split-K x2 -> x2 + Pbuf; fused reduce(+bias+x residual) + LN2
  bgemm_splitk<<<dim3(DIM / 64, NTOK / 128, 2), 256, 0, stream>>>(
      attnb, projwt, x2, Pbuf, NTOK, DIM, DIM);
  redln_kernel<<<NTOK, 256, 0, stream>>>(x2, Pbuf, projb, x, x2, ln2w, ln2b, h);

  bgemm_kernel<<<dim3(3072 / 128, NTOK / 128), 256, 0, stream>>>(
      h, l1wt, l1b, mid, NTOK, 3072, DIM, 1);

  // lin2: split-K x2 -> out + Pbuf; reduce adds bias + x2 residual
  bgemm_splitk<<<dim3(DIM / 64, NTOK / 128, 2), 256, 0, stream>>>(
      mid, l2wt, out, Pbuf, NTOK, DIM, 3072);
  red_kernel<<<NTOK * DIM / 1024, 256, 0, stream>>>(out, Pbuf, l2b, x2, out, DIM);
}

// Round 13
// 292.004 us; speedup vs baseline: 1.0685x; 1.0685x over previous
//
#include <hip/hip_runtime.h>
#include <hip/hip_bf16.h>
#include <math.h>

#define DIM 768
#define NTOK 4096   // B*N = 2*2048
#define SEQ 2048
#define HEADS 12
#define HD 64

using bf16x8 = __attribute__((ext_vector_type(8))) __bf16;
using f32x4  = __attribute__((ext_vector_type(4))) float;
typedef unsigned short u16;

__device__ inline u16 f2bf(float f) {
  union { float f; unsigned u; } v; v.f = f;
  unsigned r = v.u + 0x7fffu + ((v.u >> 16) & 1u);  // RNE
  return (u16)(r >> 16);
}

// packed f32x2 -> bf16x2 (v_cvt_pk_bf16_f32)
__device__ inline void pk2bf(float a, float b, u16* o0, u16* o1) {
  union { __hip_bfloat162 h; u16 u[2]; } cv;
  cv.h = __float22bfloat162_rn(make_float2(a, b));
  *o0 = cv.u[0];
  *o1 = cv.u[1];
}

// GELU, sigmoid form: x*sigmoid(1.5957691x + 0.0713548x^3); |err| < ~3e-3.
__device__ inline float gelu_t(float x) {
  float z = x * (1.5957691216f + 0.0713548162f * x * x);
  return x / (1.0f + __expf(-z));
}

// async global->LDS DMA, 16 B per lane; LDS dest = wave-uniform base + lane*16
__device__ inline void gl_lds16(const u16* g, u16* l) {
  __builtin_amdgcn_global_load_lds(
      (const __attribute__((address_space(1))) unsigned int*)g,
      (__attribute__((address_space(3))) unsigned int*)l, 16, 0, 0);
}

// ---------------- LayerNorm: fp32 in -> bf16 out ----------------
__global__ __launch_bounds__(256) void ln_kernel(const float* __restrict__ x,
                                                 const float* __restrict__ w,
                                                 const float* __restrict__ b,
                                                 u16* __restrict__ y) {
  int row = blockIdx.x;
  int t = threadIdx.x;
  const float* xr = x + (size_t)row * DIM;
  float v0 = xr[t], v1 = xr[t + 256], v2 = xr[t + 512];
  float s = v0 + v1 + v2;
  float q = v0 * v0 + v1 * v1 + v2 * v2;
  for (int o = 32; o > 0; o >>= 1) {
    s += __shfl_down(s, o, 64);
    q += __shfl_down(q, o, 64);
  }
  __shared__ float ws_[4], wq_[4], mb[2];
  int wid = t >> 6;
  if ((t & 63) == 0) { ws_[wid] = s; wq_[wid] = q; }
  __syncthreads();
  if (t == 0) {
    float S = ws_[0] + ws_[1] + ws_[2] + ws_[3];
    float Q = wq_[0] + wq_[1] + wq_[2] + wq_[3];
    float mean = S * (1.0f / DIM);
    float var = Q * (1.0f / DIM) - mean * mean;
    mb[0] = mean;
    mb[1] = rsqrtf(var + 1e-5f);
  }
  __syncthreads();
  float mean = mb[0], rstd = mb[1];
  u16* yr = y + (size_t)row * DIM;
  yr[t]       = f2bf((v0 - mean) * rstd * w[t]       + b[t]);
  yr[t + 256] = f2bf((v1 - mean) * rstd * w[t + 256] + b[t + 256]);
  yr[t + 512] = f2bf((v2 - mean) * rstd * w[t + 512] + b[t + 512]);
}

// -------- fused split-K reduce + residual + bias -> x2 (fp32) + LN -> h (bf16)
__global__ __launch_bounds__(256) void redln_kernel(
    const float* __restrict__ P0, const float* __restrict__ P1,
    const float* __restrict__ bias, const float* __restrict__ res,
    float* __restrict__ x2, const float* __restrict__ lnw,
    const float* __restrict__ lnb, u16* __restrict__ y) {
  int row = blockIdx.x;
  int t = threadIdx.x;
  size_t off = (size_t)row * DIM;
  float v[3];
#pragma unroll
  for (int k = 0; k < 3; ++k) {
    int c = t + k * 256;
    v[k] = P0[off + c] + P1[off + c] + bias[c] + res[off + c];
    x2[off + c] = v[k];
  }
  float s = v[0] + v[1] + v[2];
  float q = v[0] * v[0] + v[1] * v[1] + v[2] * v[2];
  for (int o = 32; o > 0; o >>= 1) {
    s += __shfl_down(s, o, 64);
    q += __shfl_down(q, o, 64);
  }
  __shared__ float ws_[4], wq_[4], mb[2];
  int wid = t >> 6;
  if ((t & 63) == 0) { ws_[wid] = s; wq_[wid] = q; }
  __syncthreads();
  if (t == 0) {
    float S = ws_[0] + ws_[1] + ws_[2] + ws_[3];
    float Q = wq_[0] + wq_[1] + wq_[2] + wq_[3];
    float mean = S * (1.0f / DIM);
    float var = Q * (1.0f / DIM) - mean * mean;
    mb[0] = mean;
    mb[1] = rsqrtf(var + 1e-5f);
  }
  __syncthreads();
  float mean = mb[0], rstd = mb[1];
#pragma unroll
  for (int k = 0; k < 3; ++k) {
    int c = t + k * 256;
    y[off + c] = f2bf((v[k] - mean) * rstd * lnw[c] + lnb[c]);
  }
}

// ---------------- all 4 weight converts in one launch (dims compile-time) ----
__global__ __launch_bounds__(256) void wcvt_all(
    const float* __restrict__ W0, const float* __restrict__ W1,
    const float* __restrict__ W2, const float* __restrict__ W3,
    u16* __restrict__ T0, u16* __restrict__ T1,
    u16* __restrict__ T2, u16* __restrict__ T3) {
  int id = blockIdx.x;
  const float* W; u16* Wt; int K, N, local;
  if (id < 1728)      { W = W0; Wt = T0; K = 768;  N = 2304; local = id; }
  else if (id < 2304) { W = W1; Wt = T1; K = 768;  N = 768;  local = id - 1728; }
  else if (id < 4608) { W = W2; Wt = T2; K = 768;  N = 3072; local = id - 2304; }
  else                { W = W3; Wt = T3; K = 3072; N = 768;  local = id - 4608; }
  int ntiles = N / 32;
  int n0 = (local % ntiles) * 32, k0 = (local / ntiles) * 32;
  __shared__ float tile[32][33];
  int tid = threadIdx.x;
  int c = tid & 31, r8 = tid >> 5;
#pragma unroll
  for (int p = 0; p < 4; ++p) {
    int k = r8 + p * 8;
    tile[k][c] = W[(size_t)(k0 + k) * N + n0 + c];
  }
  __syncthreads();
#pragma unroll
  for (int p = 0; p < 4; ++p) {
    int n = r8 + p * 8;
    Wt[(size_t)(n0 + n) * K + k0 + c] = f2bf(tile[c][n]);
  }
}

// ---------------- V transpose: qkvB V-slice -> vT[b][v][j] ----------------
__global__ __launch_bounds__(256) void vtr_kernel(const u16* __restrict__ qkvB,
                                                  u16* __restrict__ vT) {
  __shared__ u16 tile[32][33];
  int v0 = blockIdx.x * 32, j0 = blockIdx.y * 32, b = blockIdx.z;
  int tid = threadIdx.x;
  int c = tid & 31, r8 = tid >> 5;
#pragma unroll
  for (int p = 0; p < 4; ++p) {
    int r = r8 + p * 8;
    tile[r][c] = qkvB[((size_t)(b * SEQ + j0 + r)) * 2304 + 1536 + v0 + c];
  }
  __syncthreads();
#pragma unroll
  for (int p = 0; p < 4; ++p) {
    int r = r8 + p * 8;
    vT[((size_t)(b * 768 + v0 + r)) * SEQ + j0 + c] = tile[c][r];
  }
}

// ---------------- bf16 MFMA GEMM (full-K): Cb = act(A * Bt^T + bias) --------
// BK=64, DMA staging with XOR column swizzle (verified r11, bit-identical).
__global__ __launch_bounds__(256) void bgemm_kernel(
    const u16* __restrict__ A, const u16* __restrict__ Bt,
    const float* __restrict__ bias, u16* __restrict__ Cb,
    int M, int N, int K, int act) {
  __shared__ __align__(16) u16 Asl[128 * 64];
  __shared__ __align__(16) u16 Bsl[128 * 64];
  int tid = threadIdx.x;
  int lane = tid & 63, wave = tid >> 6;
  int wm = wave >> 1, wn = wave & 1;
  int bm = blockIdx.y * 128, bn = blockIdx.x * 128;
  int l15 = lane & 15, quad = lane >> 4;
  int sm8 = tid >> 3;
  int kgx = (tid & 7) ^ (sm8 & 7);

  f32x4 acc[4][4] = {};
  const u16* Ap = A + (size_t)(bm + sm8) * K + kgx * 8;
  const u16* Bp = Bt + (size_t)(bn + sm8) * K + kgx * 8;
  u16* Al = &Asl[(wave * 8) * 64];
  u16* Bl = &Bsl[(wave * 8) * 64];
  int xr = l15 & 7;

  for (int k0 = 0; k0 < K; k0 += 64) {
#pragma unroll
    for (int p = 0; p < 4; ++p)
      gl_lds16(Ap + (size_t)(p * 32) * K + k0, Al + p * 32 * 64);
#pragma unroll
    for (int p = 0; p < 4; ++p)
      gl_lds16(Bp + (size_t)(p * 32) * K + k0, Bl + p * 32 * 64);
    __syncthreads();
#pragma unroll
    for (int ks = 0; ks < 2; ++ks) {
      int pu = ((ks << 2) + quad) ^ xr;
      bf16x8 af[4], bfr[4];
#pragma unroll
      for (int i = 0; i < 4; ++i) {
        af[i]  = *(const bf16x8*)&Asl[(wm * 64 + i * 16 + l15) * 64 + pu * 8];
        bfr[i] = *(const bf16x8*)&Bsl[(wn * 64 + i * 16 + l15) * 64 + pu * 8];
      }
#pragma unroll
      for (int i = 0; i < 4; ++i)
#pragma unroll
        for (int j = 0; j < 4; ++j)
          acc[i][j] = __builtin_amdgcn_mfma_f32_16x16x32_bf16(af[i], bfr[j], acc[i][j], 0, 0, 0);
    }
    __syncthreads();
  }

#pragma unroll
  for (int i = 0; i < 4; ++i) {
#pragma unroll
    for (int j = 0; j < 4; ++j) {
      int n = bn + wn * 64 + j * 16 + l15;
      float bv = bias[n];
      float val[4];
#pragma unroll
      for (int r = 0; r < 4; ++r) {
        float v = acc[i][j][r] + bv;
        val[r] = act ? gelu_t(v) : v;
      }
      u16 c0, c1, c2, c3;
      pk2bf(val[0], val[1], &c0, &c1);
      pk2bf(val[2], val[3], &c2, &c3);
      size_t mbase = (size_t)(bm + wm * 64 + i * 16 + quad * 4) * N + n;
      Cb[mbase]         = c0;
      Cb[mbase + N]     = c1;
      Cb[mbase + 2 * N] = c2;
      Cb[mbase + 3 * N] = c3;
    }
  }
}

// ---------------- bf16 MFMA GEMM, split-K x2, 128x64 tile, BK=64 ------------
__global__ __launch_bounds__(256) void bgemm_splitk(
    const u16* __restrict__ A, const u16* __restrict__ Bt,
    float* __restrict__ P0, float* __restrict__ P1,
    int M, int N, int K) {
  __shared__ __align__(16) u16 Asl[128 * 64];
  __shared__ __align__(16) u16 Bsl[64 * 64];
  int tid = threadIdx.x;
  int lane = tid & 63, wave = tid >> 6;
  int wm = wave >> 1, wn = wave & 1;
  int bm = blockIdx.y * 128, bn = blockIdx.x * 64;
  int l15 = lane & 15, quad = lane >> 4;
  int sm8 = tid >> 3;
  int kgx = (tid & 7) ^ (sm8 & 7);
  int half = K >> 1;
  int kbeg = blockIdx.z * half;

  f32x4 acc[4][2] = {};
  const u16* Ap = A + (size_t)(bm + sm8) * K + kbeg + kgx * 8;
  const u16* Bp = Bt + (size_t)(bn + sm8) * K + kbeg + kgx * 8;
  u16* Al = &Asl[(wave * 8) * 64];
  u16* Bl = &Bsl[(wave * 8) * 64];
  int xr = l15 & 7;

  for (int k0 = 0; k0 < half; k0 += 64) {
#pragma unroll
    for (int p = 0; p < 4; ++p)
      gl_lds16(Ap + (size_t)(p * 32) * K + k0, Al + p * 32 * 64);
#pragma unroll
    for (int p = 0; p < 2; ++p)
      gl_lds16(Bp + (size_t)(p * 32) * K + k0, Bl + p * 32 * 64);
    __syncthreads();
#pragma unroll
    for (int ks = 0; ks < 2; ++ks) {
      int pu = ((ks << 2) + quad) ^ xr;
      bf16x8 af[4], bfr[2];
#pragma unroll
      for (int i = 0; i < 4; ++i)
        af[i] = *(const bf16x8*)&Asl[(wm * 64 + i * 16 + l15) * 64 + pu * 8];
#pragma unroll
      for (int j = 0; j < 2; ++j)
        bfr[j] = *(const bf16x8*)&Bsl[(wn * 32 + j * 16 + l15) * 64 + pu * 8];
#pragma unroll
      for (int i = 0; i < 4; ++i)
#pragma unroll
        for (int j = 0; j < 2; ++j)
          acc[i][j] = __builtin_amdgcn_mfma_f32_16x16x32_bf16(af[i], bfr[j], acc[i][j], 0, 0, 0);
    }
    __syncthreads();
  }

  float* P = blockIdx.z ? P1 : P0;
#pragma unroll
  for (int i = 0; i < 4; ++i) {
#pragma unroll
    for (int j = 0; j < 2; ++j) {
      int n = bn + wn * 32 + j * 16 + l15;
#pragma unroll
      for (int r = 0; r < 4; ++r) {
        int m = bm + wm * 64 + i * 16 + quad * 4 + r;
        P[(size_t)m * N + n] = acc[i][j][r];
      }
    }
  }
}

// ---------------- split-K reduce: O = P0 + P1 + bias + res ------------------
__global__ __launch_bounds__(256) void red_kernel(
    const float* P0, const float* __restrict__ P1,
    const float* __restrict__ bias, const float* __restrict__ res,
    float* O, int Ncols) {
  int i = blockIdx.x * 256 + threadIdx.x;
  float4 a = ((const float4*)P0)[i];
  float4 b = ((const float4*)P1)[i];
  float4 r = ((const float4*)res)[i];
  int col = (i * 4) % Ncols;
  float4 bi = *(const float4*)&bias[col];
  float4 o;
  o.x = a.x + b.x + r.x + bi.x;
  o.y = a.y + b.y + r.y + bi.y;
  o.z = a.z + b.z + r.z + bi.z;
  o.w = a.w + b.w + r.w + bi.w;
  ((float4*)O)[i] = o;
}

// ---------------- 4-wave MFMA flash attention, DMA-staged + double-buffered --
// r11 4-wave structure (12 waves/CU TLP — r12 showed 1-wave loses 24% to
// latency exposure) with r12's staging wins: K/V/Q via global_load_lds using
// the r11-verified stride-64 XOR column swizzle (unit p of row r holds global
// unit p^(r&7)); K/V double-buffered, prefetch issued at tile top (the
// mid-tile P-barrier's vmcnt drain lands ~800cyc after issue -> latency
// hidden). P path byte-identical to r9/r11 (AST=72, jt^quad block-of-16).
#define AST 72
__global__ __launch_bounds__(256) void attn_kernel(const u16* __restrict__ qkv,
                                                   const u16* __restrict__ vT,
                                                   u16* __restrict__ out) {
  __shared__ __align__(16) u16 Qs[64 * 64];
  __shared__ __align__(16) u16 Ks[2][64 * 64];
  __shared__ __align__(16) u16 Vs[2][64 * 64];
  __shared__ u16 Ps[64 * AST];

  int tid = threadIdx.x;
  int lane = tid & 63, wave = tid >> 6;
  int l15 = lane & 15, quad = lane >> 4;
  int qt = blockIdx.x * 64;
  int h = blockIdx.y, b = blockIdx.z;
  size_t base = (size_t)b * SEQ;
  int srow = lane >> 3;                 // 0..7 within an 8-row DMA chunk
  int sux = (lane & 7) ^ (srow & 7);    // XOR-swizzled global 16B col-unit
  int r0 = wave * 16;                   // this wave's staging row base
  const u16* qbase = qkv + (base + qt) * 2304 + h * HD;
  const u16* kbase = qkv + base * 2304 + 768 + h * HD;
  const u16* vbase = vT + ((size_t)(b * HEADS + h) * HD) * SEQ;

  // stage Q + K/V tile 0 (wave w covers rows r0..r0+15 = two 8-row chunks)
  gl_lds16(qbase + (size_t)(r0 + srow) * 2304 + sux * 8, Qs + r0 * 64);
  gl_lds16(qbase + (size_t)(r0 + 8 + srow) * 2304 + sux * 8, Qs + (r0 + 8) * 64);
  gl_lds16(kbase + (size_t)(r0 + srow) * 2304 + sux * 8, Ks[0] + r0 * 64);
  gl_lds16(kbase + (size_t)(r0 + 8 + srow) * 2304 + sux * 8, Ks[0] + (r0 + 8) * 64);
  gl_lds16(vbase + (size_t)(r0 + srow) * SEQ + sux * 8, Vs[0] + r0 * 64);
  gl_lds16(vbase + (size_t)(r0 + 8 + srow) * SEQ + sux * 8, Vs[0] + (r0 + 8) * 64);
  __syncthreads();

  int xr = l15 & 7;
  bf16x8 aq0 = *(const bf16x8*)&Qs[(wave * 16 + l15) * 64 + ((quad ^ xr)) * 8];
  bf16x8 aq1 = *(const bf16x8*)&Qs[(wave * 16 + l15) * 64 + (((4 + quad) ^ xr)) * 8];

  f32x4 o_acc[4] = {};
  float l_part[4] = {0.f, 0.f, 0.f, 0.f};
  int sw = l15 >> 2;  // P-read: quad of the writer of row wave*16+l15

  for (int t = 0; t < 32; ++t) {
    int buf = t & 1;
    if (t < 31) {  // prefetch next K/V tile into the other buffer
      size_t kt1 = (size_t)(t + 1) * 64;
      gl_lds16(kbase + (kt1 + r0 + srow) * 2304 + sux * 8, Ks[buf ^ 1] + r0 * 64);
      gl_lds16(kbase + (kt1 + r0 + 8 + srow) * 2304 + sux * 8, Ks[buf ^ 1] + (r0 + 8) * 64);
      gl_lds16(vbase + (size_t)(r0 + srow) * SEQ + kt1 + sux * 8, Vs[buf ^ 1] + r0 * 64);
      gl_lds16(vbase + (size_t)(r0 + 8 + srow) * SEQ + kt1 + sux * 8, Vs[buf ^ 1] + (r0 + 8) * 64);
    }

    f32x4 s_acc[4] = {};
#pragma unroll
    for (int jt = 0; jt < 4; ++jt) {
      bf16x8 bk0 = *(const bf16x8*)&Ks[buf][(jt * 16 + l15) * 64 + ((quad ^ xr)) * 8];
      s_acc[jt] = __builtin_amdgcn_mfma_f32_16x16x32_bf16(aq0, bk0, s_acc[jt], 0, 0, 0);
      bf16x8 bk1 = *(const bf16x8*)&Ks[buf][(jt * 16 + l15) * 64 + (((4 + quad) ^ xr)) * 8];
      s_acc[jt] = __builtin_amdgcn_mfma_f32_16x16x32_bf16(aq1, bk1, s_acc[jt], 0, 0, 0);
    }

    // max-free softmax: p = exp(s/8); P stored bf16, col-tile jt at jt^quad.
#pragma unroll
    for (int r = 0; r < 4; ++r) {
      float p0 = __expf(s_acc[0][r] * 0.125f);
      float p1 = __expf(s_acc[1][r] * 0.125f);
      float p2 = __expf(s_acc[2][r] * 0.125f);
      float p3 = __expf(s_acc[3][r] * 0.125f);
      l_part[r] += p0 + p1 + p2 + p3;
      u16 b0, b1, b2, b3;
      pk2bf(p0, p1, &b0, &b1);
      pk2bf(p2, p3, &b2, &b3);
      int prow = (wave * 16 + quad * 4 + r) * AST;
      Ps[prow + ((0 ^ quad) * 16) + l15] = b0;
      Ps[prow + ((1 ^ quad) * 16) + l15] = b1;
      Ps[prow + ((2 ^ quad) * 16) + l15] = b2;
      Ps[prow + ((3 ^ quad) * 16) + l15] = b3;
    }
    __syncthreads();  // P write->read order (also drains prefetch DMAs, ~800cyc after issue)

    // O += P V
#pragma unroll
    for (int ks = 0; ks < 2; ++ks) {
      int blk = ks * 2 + (quad >> 1);
      bf16x8 ap = *(const bf16x8*)&Ps[(wave * 16 + l15) * AST + ((blk ^ sw) * 16) + (quad & 1) * 8];
#pragma unroll
      for (int dt = 0; dt < 4; ++dt) {
        bf16x8 bv = *(const bf16x8*)&Vs[buf][(dt * 16 + l15) * 64 + (((ks << 2) + quad) ^ xr) * 8];
        o_acc[dt] = __builtin_amdgcn_mfma_f32_16x16x32_bf16(ap, bv, o_acc[dt], 0, 0, 0);
      }
    }
    __syncthreads();  // all Ks/Vs[buf] + Ps reads done before next tile reuses them
  }

#pragma unroll
  for (int r = 0; r < 4; ++r) {
    float l = l_part[r];
    for (int msk = 1; msk < 16; msk <<= 1) l += __shfl_xor(l, msk, 64);
    l_part[r] = 1.0f / l;
  }

#pragma unroll
  for (int r = 0; r < 4; ++r) {
    size_t trow = (base + qt + wave * 16 + quad * 4 + r) * DIM + h * HD;
    u16 c0, c1, c2, c3;
    pk2bf(o_acc[0][r] * l_part[r], o_acc[1][r] * l_part[r], &c0, &c1);
    pk2bf(o_acc[2][r] * l_part[r], o_acc[3][r] * l_part[r], &c2, &c3);
    out[trow + 0 * 16 + l15] = c0;
    out[trow + 1 * 16 + l15] = c1;
    out[trow + 2 * 16 + l15] = c2;
    out[trow + 3 * 16 + l15] = c3;
  }
}

extern "C" void kernel_launch(void* const* d_in, const int* in_sizes, int n_in,
                              void* d_out, int out_size, void* d_ws, size_t ws_size,
                              hipStream_t stream) {
  const float* x     = (const float*)d_in[0];
  const float* ln1w  = (const float*)d_in[1];
  const float* ln1b  = (const float*)d_in[2];
  const float* qkvw  = (const float*)d_in[3];
  const float* qkvbi = (const float*)d_in[4];
  const float* projw = (const float*)d_in[5];
  const float* projb = (const float*)d_in[6];
  const float* ln2w  = (const float*)d_in[7];
  const float* ln2b  = (const float*)d_in[8];
  const float* l1w   = (const float*)d_in[9];
  const float* l1b   = (const float*)d_in[10];
  const float* l2w   = (const float*)d_in[11];
  const float* l2b   = (const float*)d_in[12];
  float* out = (float*)d_out;

  char* w = (char*)d_ws;
  u16*   h     = (u16*)w;   w += (size_t)NTOK * DIM * 2;          // 6.3 MB
  u16*   qkvB  = (u16*)w;                                         // 18.9 MB (union)
  u16*   mid   = (u16*)w;   w += (size_t)NTOK * 3072 * 2;         // 25.2 MB union
  u16*   attnb = (u16*)w;   w += (size_t)NTOK * DIM * 2;          // 6.3 MB
  float* x2    = (float*)w; w += (size_t)NTOK * DIM * 4;          // 12.6 MB
  u16*   vTb   = (u16*)w;   w += (size_t)NTOK * DIM * 2;          // 6.3 MB
  u16*   qkvwt = (u16*)w;   w += (size_t)DIM * 2304 * 2;
  u16*   projwt= (u16*)w;   w += (size_t)DIM * DIM * 2;
  u16*   l1wt  = (u16*)w;   w += (size_t)DIM * 3072 * 2;
  u16*   l2wt  = (u16*)w;   w += (size_t)3072 * DIM * 2;
  float* Pbuf  = (float*)w; w += (size_t)NTOK * DIM * 4;          // 12.6 MB (split-K P1)

  wcvt_all<<<6912, 256, 0, stream>>>(qkvw, projw, l1w, l2w,
                                     qkvwt, projwt, l1wt, l2wt);

  ln_kernel<<<NTOK, 256, 0, stream>>>(x, ln1w, ln1b, h);
  bgemm_kernel<<<dim3(2304 / 128, NTOK / 128), 256, 0, stream>>>(
      h, qkvwt, qkvbi, qkvB, NTOK, 2304, DIM, 0);
  vtr_kernel<<<dim3(768 / 32, SEQ / 32, 2), 256, 0, stream>>>(qkvB, vTb);
  attn_kernel<<<dim3(SEQ / 64, HEADS, 2), 256, 0, stream>>>(qkvB, vTb, attnb);

  // proj: split-K x2 -> x2 + Pbuf; fused reduce(+bias+x residual) + LN2
  bgemm_splitk<<<dim3(DIM / 64, NTOK / 128, 2), 256, 0, stream>>>(
      attnb, projwt, x2, Pbuf, NTOK, DIM, DIM);
  redln_kernel<<<NTOK, 256, 0, stream>>>(x2, Pbuf, projb, x, x2, ln2w, ln2b, h);

  bgemm_kernel<<<dim3(3072 / 128, NTOK / 128), 256, 0, stream>>>(
      h, l1wt, l1b, mid, NTOK, 3072, DIM, 1);

  // lin2: split-K x2 -> out + Pbuf; reduce adds bias + x2 residual
  bgemm_splitk<<<dim3(DIM / 64, NTOK / 128, 2), 256, 0, stream>>>(
      mid, l2wt, out, Pbuf, NTOK, DIM, 3072);
  red_kernel<<<NTOK * DIM / 1024, 256, 0, stream>>>(out, Pbuf, l2b, x2, out, DIM);
}